// Round 6
// baseline (97.617 us; speedup 1.0000x reference)
//
#include <hip/hip_runtime.h>
#include <hip/hip_fp16.h>

// Problem constants (fixed by reference): B=512, F=8, D=4, R=32, U=64
#define NB 512
#define NF 8
#define ND 4
#define NR 32
#define NU 64
#define G  4   // batches (b) per wave

typedef float f32x4 __attribute__((ext_vector_type(4)));
typedef unsigned u32x4 __attribute__((ext_vector_type(4)));
typedef _Float16 f16x8 __attribute__((ext_vector_type(8)));

// ---- f16 packed math, inline asm (PROVEN R14/R15: main 61.3 -> 41.8us,
// absmax 0.25). VOP3P one-SGPR-source via "s" constraint (proven R11).
// Asm opaque to optimizer (R9: native vector ops get reassociated).
__device__ inline unsigned pkmul_h(unsigned a, unsigned s) {
    unsigned d;
    asm("v_pk_mul_f16 %0, %1, %2" : "=v"(d) : "v"(a), "s"(s));
    return d;
}
__device__ inline unsigned pkfma_h(unsigned a, unsigned s, unsigned c) {
    unsigned d;
    asm("v_pk_fma_f16 %0, %1, %2, %3" : "=v"(d) : "v"(a), "s"(s), "v"(c));
    return d;
}

// f32 pair -> packed f16 word, RTZ, single instruction (v_cvt_pkrtz_f16_f32).
// lo = first arg. PROVEN R14/R15 for both X broadcast and N' writeback.
__device__ inline unsigned pkrtz(float a, float b) {
    auto h = __builtin_amdgcn_cvt_pkrtz(a, b);
    static_assert(sizeof(h) == 4, "cvt_pkrtz must return 32-bit");
    return __builtin_bit_cast(unsigned, h);
}

// f32 pair -> packed f16 word, RNE (K pre-pass; K deserves round-nearest)
__device__ inline unsigned h2pack(float a, float b) {
    unsigned ha = (unsigned)__half_as_ushort(__float2half(a));
    unsigned hb = (unsigned)__half_as_ushort(__float2half(b));
    return ha | (hb << 16);
}

// wave-uniform u32 -> SGPR (readfirstlane; value unchanged)
__device__ inline unsigned rfl_u(unsigned v) {
    return (unsigned)__builtin_amdgcn_readfirstlane((int)v);
}

// ---------------------------------------------------------------------------
// Pre-pass (R16-proven split, K-only): 512 blocks (u split 16 per block),
// ~5us vs the 256-block version's ~10us. R16's X-pack blocks are DROPPED
// (the Xh s_load path in main is the prime suspect for R16's regression).
//   K3h u32 index = (u*8+f)*2048 + (q*4+jp)*128 + (I*16+c)*4 + d
//   word = half2( K[d][e_par0], K[d][e_par1] ),  e = 256q+64jp+32par+16I+c
// ---------------------------------------------------------------------------
__global__ __launch_bounds__(256) void tr_k3h17(const float* __restrict__ K,
                                                unsigned* __restrict__ K3h) {
    __shared__ float lds[256 * 20];   // rows (d*64+s) x 16 u, pad to 20
    const int t   = threadIdx.x;
    const int bid = blockIdx.x;
    const int uq = bid & 3, jp = (bid >> 2) & 3, q = (bid >> 4) & 3, f = bid >> 6;
    const int u0 = uq * 16;

    {   // read phase: rows r = d*64 + s, 16 floats of u each
        const int rr = t >> 2, col4 = (t & 3) * 4;
#pragma unroll
        for (int i = 0; i < 4; ++i) {
            int r = i * 64 + rr;              // 0..255
            int d = r >> 6, s = r & 63;
            int e = q * 256 + jp * 64 + s;
            f32x4 v = *(const f32x4*)(K + ((size_t)((d << 10) + e) << 9)
                                        + (f << 6) + u0 + col4);
            *(f32x4*)(lds + r * 20 + col4) = v;
        }
    }
    __syncthreads();
    {   // write phase: per u_l, f16-pair emit (8B per thread-iter)
        const int u_l = t >> 4, lane16 = t & 15;  // u_l 0..15
        unsigned* dst = K3h + ((size_t)((u0 + u_l) * 8 + f) << 11)
                            + ((q * 4 + jp) << 7);
#pragma unroll
        for (int g2 = 0; g2 < 4; ++g2) {
            int idx4 = lane16 + g2 * 16;      // 0..63
            int dh = idx4 & 1, Ic = idx4 >> 1;  // Ic = I*16+c in 0..31
            int d0 = dh * 2;
            float v0 = lds[(d0 * 64 + 0  + Ic) * 20 + u_l];   // d0, par0
            float v1 = lds[(d0 * 64 + 32 + Ic) * 20 + u_l];   // d0, par1
            float v2 = lds[((d0 + 1) * 64 + 0  + Ic) * 20 + u_l];
            float v3 = lds[((d0 + 1) * 64 + 32 + Ic) * 20 + u_l];
            uint2 wv; wv.x = h2pack(v0, v1); wv.y = h2pack(v2, v3);
            *(uint2*)(dst + idx4 * 2) = wv;   // words (Ic*4+2dh), (+1)
        }
    }
}

// ---------------------------------------------------------------------------
// Main R17 = R15 (proven 41.8us, absmax 0.25) + ONLY the cross-f K prefetch
// from R16 (correctness-proven there; perf untested in isolation).
// R16 post-mortem: bench total was FLAT while rocprof main "rose" to 63us
// -- arithmetic says bench-mode main was ~46us and the rocprof reading was
// inflated by replay cache-flushing hitting the Xh s_load path. The Xh
// change (X via SMEM) is REVERTED: X returns to the R15 VMEM+pkrtz+rfl
// path whose latency merges with the K-load stall under one vmcnt wait.
// The prefetch keeps jp=3 (otherwise load-free) issuing next-f's jp=0
// words so they land during the MFMA phase instead of stalling A-phase
// entry. +8 VGPR live across MFMA (budget 64; WRITE_SIZE is the tripwire).
// Pre-committed read: rocprof main <=41 -> prefetch confirmed; >=45 ->
// prefetch is the regressor, revert next round.
// Discriminators: absmax EXACTLY 0.25, main ~38-41us, bench ~88-91us,
// WRITE_SIZE ~1MB, VGPR <= 64, FETCH ~2700KB.
// ---------------------------------------------------------------------------
__global__ __launch_bounds__(128)
__attribute__((amdgpu_waves_per_eu(4, 4)))
void tr_main17(const float* __restrict__ X,
               const unsigned* __restrict__ K3h,
               float* __restrict__ out) {
    const int tid  = threadIdx.x;
    const int w    = __builtin_amdgcn_readfirstlane(tid >> 6);  // wave id, SGPR
    const int lane = tid & 63;
    const int c    = lane & 15;
    const int q    = lane >> 4;
    const int u      = blockIdx.x & 63;               // u-minor (R3/R7-proven)
    const int bgroup = blockIdx.x >> 6;               // 0..63
    const int b0     = ((bgroup << 1) + w) * G;       // SGPR-computed

    __shared__ __attribute__((aligned(16))) char lds[2 * G * 2048];
    char* Nb0 = lds + w * (G * 2048);

    // identity B-frags for f=0: B[k=8q+j][n=c(+16)]; f16 1.0 = 0x3C00 exact
    f16x8 idf0, idf1;
#pragma unroll
    for (int jj = 0; jj < 8; ++jj) {
        idf0[jj] = (8 * q + jj == c) ? (_Float16)1.0f : (_Float16)0.0f;
        idf1[jj] = (8 * q + jj == 16 + c) ? (_Float16)1.0f : (_Float16)0.0f;
    }

    const unsigned* Kt = K3h + ((size_t)u << 14) + (q << 9) + (c << 2);
    const f32x4 z = {0.f, 0.f, 0.f, 0.f};

    // f=0 jp=0 K words, issued before the loop (prefetch seed)
    u32x4 s0 = *(const u32x4*)(Kt + 0);       // (f=0, jp=0, I=0)
    u32x4 s1 = *(const u32x4*)(Kt + 64);      // (f=0, jp=0, I=1)

#pragma unroll
    for (int f = 0; f < NF; ++f) {
        const unsigned* Kf = Kt + (f << 11);

        // ---- X broadcasts (R15-proven): VMEM load + pkrtz + rfl ----
        unsigned xdd[G][4];
#pragma unroll
        for (int g = 0; g < G; ++g) {
            const f32x4 xv = *(const f32x4*)(X + ((b0 + g) << 5) + (f << 2));
#pragma unroll
            for (int d = 0; d < 4; ++d)
                xdd[g][d] = rfl_u(pkrtz(xv[d], xv[d]));
        }

        // ---- A-phase: jp-outer, g-inner; 1-deep staging prefetch that
        //      crosses the f boundary at jp=3 (lands during MFMA phase) ----
        u32x4 A0u[G], A1u[G];
#pragma unroll
        for (int jp = 0; jp < 4; ++jp) {
            u32x4 c0 = s0, c1 = s1;
            if (jp < 3) {
                const unsigned* pn = Kf + ((jp + 1) << 7);
                s0 = *(const u32x4*)(pn + 0);
                s1 = *(const u32x4*)(pn + 64);
            } else if (f < NF - 1) {
                const unsigned* pn = Kf + 2048;   // next f, jp=0
                s0 = *(const u32x4*)(pn + 0);
                s1 = *(const u32x4*)(pn + 64);
            }
#pragma unroll
            for (int g = 0; g < G; ++g) {
                {   // I = 0: A-word = (T[e_par0], T[e_par1]) f16
                    unsigned tv = pkmul_h(c0[0], xdd[g][0]);
                    tv = pkfma_h(c0[1], xdd[g][1], tv);
                    tv = pkfma_h(c0[2], xdd[g][2], tv);
                    tv = pkfma_h(c0[3], xdd[g][3], tv);
                    A0u[g][jp] = tv;
                }
                {   // I = 1
                    unsigned tv = pkmul_h(c1[0], xdd[g][0]);
                    tv = pkfma_h(c1[1], xdd[g][1], tv);
                    tv = pkfma_h(c1[2], xdd[g][2], tv);
                    tv = pkfma_h(c1[3], xdd[g][3], tv);
                    A1u[g][jp] = tv;
                }
            }
        }

        // ---- MFMA phase per g (UNCHANGED R14/R15) ----
#pragma unroll
        for (int g = 0; g < G; ++g) {
            char* nb = Nb0 + (g << 11);
            f16x8 A0 = __builtin_bit_cast(f16x8, A0u[g]);
            f16x8 A1 = __builtin_bit_cast(f16x8, A1u[g]);

            f16x8 bf0, bf1;
            if (f == 0) { bf0 = idf0; bf1 = idf1; }
            else {
                bf0 = *(const f16x8*)(nb + (((q << 5) | c) << 4));
                bf1 = *(const f16x8*)(nb + (((q << 5) | c) << 4) + 256);
            }

            if (f < NF - 1) {
                f32x4 c00 = __builtin_amdgcn_mfma_f32_16x16x32_f16(A0, bf0, z, 0, 0, 0);
                f32x4 c01 = __builtin_amdgcn_mfma_f32_16x16x32_f16(A0, bf1, z, 0, 0, 0);
                f32x4 c10 = __builtin_amdgcn_mfma_f32_16x16x32_f16(A1, bf0, z, 0, 0, 0);
                f32x4 c11 = __builtin_amdgcn_mfma_f32_16x16x32_f16(A1, bf1, z, 0, 0, 0);
                // writeback N' (f16) for next f
#pragma unroll
                for (int I = 0; I < 2; ++I)
#pragma unroll
                    for (int J = 0; J < 2; ++J) {
                        f32x4 a = (I == 0) ? (J == 0 ? c00 : c01)
                                           : (J == 0 ? c10 : c11);
                        unsigned lo = pkrtz(a[0], a[1]);
                        unsigned hi = pkrtz(a[2], a[3]);
                        uint2 val; val.x = lo; val.y = hi;
                        // slot(p = 2I + (q>>1), n = 16J + c), byte +8*(q&1)
                        *(uint2*)(nb + (((((I << 1) | (q >> 1)) << 5) | (J << 4) | c) << 4)
                                     + ((q & 1) << 3)) = val;
                    }
            } else {
                // last step: only diagonal tiles feed the trace
                f32x4 c00 = __builtin_amdgcn_mfma_f32_16x16x32_f16(A0, bf0, z, 0, 0, 0);
                f32x4 c11 = __builtin_amdgcn_mfma_f32_16x16x32_f16(A1, bf1, z, 0, 0, 0);
                f32x4 t4 = c00 + c11;
                int ri = c & 3;
                float s = (ri == 0) ? t4[0] : (ri == 1) ? t4[1]
                        : (ri == 2) ? t4[2] : t4[3];
                s = ((c >> 2) == q) ? s : 0.f;
#pragma unroll
                for (int m = 32; m >= 1; m >>= 1) s += __shfl_xor(s, m, 64);
                if (lane == 0) out[((b0 + g) << 6) + u] = s;
            }
        }
        // Compiler memory fence: this-f LDS writes must precede next-f LDS
        // reads in program order (HW DS pipe is in-order per wave; only the
        // compiler could break it). Zero instructions emitted. The cross-f
        // K prefetch is issued BEFORE this fence by design.
        asm volatile("" ::: "memory");
    }
}

extern "C" void kernel_launch(void* const* d_in, const int* in_sizes, int n_in,
                              void* d_out, int out_size, void* d_ws, size_t ws_size,
                              hipStream_t stream) {
    (void)in_sizes; (void)n_in; (void)out_size; (void)ws_size;
    const float* X = (const float*)d_in[0];   // [512][8][4]
    const float* K = (const float*)d_in[1];   // [4][32][32][8][64]
    float* out = (float*)d_out;               // [512][64]
    unsigned* K3h = (unsigned*)d_ws;          // 4 MB, f16 par-pair words

    hipLaunchKernelGGL(tr_k3h17, dim3(512), dim3(256), 0, stream, K, K3h);
    hipLaunchKernelGGL(tr_main17, dim3(4096), dim3(128), 0, stream, X, K3h, out);
}